// Round 1
// baseline (3252.118 us; speedup 1.0000x reference)
//
#include <hip/hip_runtime.h>

typedef unsigned short u16;
typedef __attribute__((ext_vector_type(4))) float v4f;
typedef __attribute__((ext_vector_type(8))) short bf16x8;

#define B_ 8
#define T_ 2048
#define D_ 1024
#define NH_ 8
#define DH_ 128
#define H_ 1024
#define P_ 1365
#define PPAD_ 1408   // P padded to multiple of 128 (up-GEMM N, down-GEMM K)
#define M_ 16384     // B*T

// ---------- bf16 helpers (manual RNE) ---------------------------------------
__device__ __forceinline__ u16 f2b(float f) {
    union { float f; unsigned u; } v; v.f = f;
    unsigned r = (v.u + 0x7fffu + ((v.u >> 16) & 1u)) >> 16;
    return (u16)r;
}
__device__ __forceinline__ float b2f(u16 u) {
    union { unsigned u; float f; } v; v.u = ((unsigned)u) << 16;
    return v.f;
}
// fast tanh via hardware exp+rcp (err ~1e-6, way below bf16 noise)
__device__ __forceinline__ float ftanh(float x) {
    float e = __expf(2.f * x);
    return 1.f - 2.f * __builtin_amdgcn_rcpf(e + 1.f);
}
__device__ __forceinline__ float softcap15(float x) {
    return 15.f * ftanh(x * (1.f / 15.f));
}

// async global->LDS, 16B per lane; lds ptr must be wave-uniform
#define GLD16(gp, lp) __builtin_amdgcn_global_load_lds( \
    (const __attribute__((address_space(1))) void*)(gp), \
    (__attribute__((address_space(3))) void*)(lp), 16, 0, 0)

// ---------------- transpose + cast fp32 -> bf16 ------------------------------
// output row index = n*rowmul + rowoff (lets the 4 gate weights interleave
// their columns: WT4i[nh*4+g][k], so gate-GEMM output is [t][nh][g] packed)
__global__ __launch_bounds__(256) void transpose_cast(
    const float* __restrict__ in, u16* __restrict__ out,
    int K, int N, int Kpad, int Npad, int ldin, int rowmul, int rowoff)
{
    __shared__ float tile[32][33];
    const int tx = threadIdx.x, ty = threadIdx.y;
    const int nblk = blockIdx.x * 32, kblk = blockIdx.y * 32;
#pragma unroll
    for (int i = 0; i < 4; ++i) {
        int k = kblk + ty + i * 8, n = nblk + tx;
        float v = (k < K && n < N) ? in[(size_t)k * ldin + n] : 0.f;
        tile[ty + i * 8][tx] = v;
    }
    __syncthreads();
#pragma unroll
    for (int i = 0; i < 4; ++i) {
        int n = nblk + ty + i * 8, k = kblk + tx;
        if (n < Npad && k < Kpad)
            out[((size_t)n * rowmul + rowoff) * Kpad + k] = f2b(tile[tx][ty + i * 8]);
    }
}

// ---------------- concat 4 per-gate vectors [1024] -> interleaved [1024][4] -
__global__ __launch_bounds__(256) void bias4_concat(
    const float* __restrict__ bz, const float* __restrict__ bi,
    const float* __restrict__ bo, const float* __restrict__ bf,
    float* __restrict__ b4)
{
    int j = blockIdx.x * 256 + threadIdx.x;  // 0..4095
    const float* p = (j < 1024) ? bz : (j < 2048) ? bi : (j < 3072) ? bo : bf;
    b4[((j & 1023) << 2) | (j >> 10)] = p[j & 1023];
}

// ---------------- pack R into MFMA A-layout: RQ[hd][m=e*4+g][d] bf16 --------
__global__ __launch_bounds__(128) void rq_prep(
    const float* __restrict__ Rz, const float* __restrict__ Ri,
    const float* __restrict__ Ro, const float* __restrict__ Rf,
    u16* __restrict__ RQ)
{
    const int m = blockIdx.x;      // 0..511
    const int hd = blockIdx.y;     // 0..7
    const int d = threadIdx.x;     // 0..127
    const int g = m & 3, e = m >> 2;
    const float* Rg = (g == 0) ? Rz : (g == 1) ? Ri : (g == 2) ? Ro : Rf;
    RQ[((size_t)hd * 512 + m) * 128 + d] =
        f2b(Rg[((size_t)hd * 128 + d) * 128 + e]);
}

// ---------------- LayerNorm over D=1024 + cast to bf16 ----------------------
__global__ __launch_bounds__(256) void ln_cast_kernel(
    const float* __restrict__ x, const float* __restrict__ w,
    const float* __restrict__ b, u16* __restrict__ xnb)
{
    const int token = blockIdx.x, tid = threadIdx.x;
    const float4* xr = (const float4*)(x + (size_t)token * D_);
    float4 v = xr[tid];
    float s  = v.x + v.y + v.z + v.w;
    float ss = v.x * v.x + v.y * v.y + v.z * v.z + v.w * v.w;
    for (int off = 32; off; off >>= 1) { s += __shfl_down(s, off); ss += __shfl_down(ss, off); }
    __shared__ float wsum[4], wsq[4], stats[2];
    const int wave = tid >> 6, lane = tid & 63;
    if (lane == 0) { wsum[wave] = s; wsq[wave] = ss; }
    __syncthreads();
    if (tid == 0) {
        float S = 0.f, SS = 0.f;
        for (int i = 0; i < 4; ++i) { S += wsum[i]; SS += wsq[i]; }
        float mu = S * (1.f / 1024.f);
        float var = SS * (1.f / 1024.f) - mu * mu;
        stats[0] = mu; stats[1] = rsqrtf(var + 1e-6f);
    }
    __syncthreads();
    const float mu = stats[0], rs = stats[1];
    float4 wv = ((const float4*)w)[tid];
    float4 bv = ((const float4*)b)[tid];
    ushort4 o;
    o.x = f2b((v.x - mu) * rs * wv.x + bv.x);
    o.y = f2b((v.y - mu) * rs * wv.y + bv.y);
    o.z = f2b((v.z - mu) * rs * wv.z + bv.z);
    o.w = f2b((v.w - mu) * rs * wv.w + bv.w);
    ((ushort4*)(xnb + (size_t)token * D_))[tid] = o;
}

// ---------------- m97-style bf16 MFMA GEMM core (128x128 tile, BK=32) -------
__device__ __forceinline__ void gemm128_core(
    const u16* __restrict__ A, const u16* __restrict__ BT,
    int K, int m0, int n0, v4f acc[4][4])
{
    __shared__ __align__(16) u16 As[4096];  // [128][32]
    __shared__ __align__(16) u16 Bs[4096];  // [128][32]
    const int tid = threadIdx.x;
    const int wave = tid >> 6, lane = tid & 63;
    const int wm = wave & 1, wn = wave >> 1;
    const int srow = tid >> 2, sseg = tid & 3;
    const int lm = lane & 15, lq = lane >> 4;

    const u16* gA0 = A  + (size_t)(m0 + srow) * K + sseg * 8;
    const u16* gA1 = gA0 + (size_t)64 * K;
    const u16* gB0 = BT + (size_t)(n0 + srow) * K + sseg * 8;
    const u16* gB1 = gB0 + (size_t)64 * K;
    u16* lA0 = As + wave * 512;
    u16* lA1 = As + 2048 + wave * 512;
    u16* lB0 = Bs + wave * 512;
    u16* lB1 = Bs + 2048 + wave * 512;

    for (int kk = 0; kk < K; kk += 32) {
        GLD16(gA0 + kk, lA0);
        GLD16(gA1 + kk, lA1);
        GLD16(gB0 + kk, lB0);
        GLD16(gB1 + kk, lB1);
        __syncthreads();
        bf16x8 a[4], b[4];
#pragma unroll
        for (int i = 0; i < 4; ++i) {
            a[i] = *(const bf16x8*)(As + (wm * 64 + i * 16 + lm) * 32 + lq * 8);
            b[i] = *(const bf16x8*)(Bs + (wn * 64 + i * 16 + lm) * 32 + lq * 8);
        }
#pragma unroll
        for (int i = 0; i < 4; ++i)
#pragma unroll
            for (int j = 0; j < 4; ++j)
                acc[i][j] = __builtin_amdgcn_mfma_f32_16x16x32_bf16(a[i], b[j], acc[i][j], 0, 0, 0);
        __syncthreads();
    }
}

// ---------------- fused 4-gate GEMM (N=4096, cols = nh*4+g interleaved) -----
__global__ __launch_bounds__(256) void gemm_gate4(
    const u16* __restrict__ A, const u16* __restrict__ WT4,
    const float* __restrict__ bias4, u16* __restrict__ gx4,
    int t0, int Tc)
{
    v4f acc[4][4];
#pragma unroll
    for (int i = 0; i < 4; ++i)
#pragma unroll
        for (int j = 0; j < 4; ++j)
#pragma unroll
            for (int r = 0; r < 4; ++r) acc[i][j][r] = 0.f;
    const int mtPerB = Tc >> 7;
    const int b_ = blockIdx.y / mtPerB, tt = blockIdx.y % mtPerB;
    const int m0 = b_ * T_ + t0 + tt * 128;
    const int n0 = blockIdx.x * 128;
    gemm128_core(A, WT4, D_, m0, n0, acc);
    const int r0 = b_ * Tc + tt * 128;   // row in chunk space
    const int tid = threadIdx.x, wave = tid >> 6, lane = tid & 63;
    const int wm = wave & 1, wn = wave >> 1;
    const int col = lane & 15, rb0 = (lane >> 4) * 4;
#pragma unroll
    for (int j = 0; j < 4; ++j) {
        const int n = n0 + wn * 64 + j * 16 + col;
        const float bv = bias4[n];
#pragma unroll
        for (int i = 0; i < 4; ++i)
#pragma unroll
            for (int r = 0; r < 4; ++r) {
                const int rr = r0 + wm * 64 + i * 16 + rb0 + r;
                gx4[(size_t)rr * 4096 + n] = f2b(acc[i][j][r] + bv);
            }
    }
}

// ---------------- MFMA sequential scan, fused gate math ---------------------
// One WG per (batch, head). 512 thr = 8 waves. Per step:
//   ds_read B-frag (h, MFMA-linear, conflict-free) -> 16 MFMA ->
//   col-0 lanes (lane%16==0) hold all 4 gates of e=16w+4i+lq in acc[i]
//   -> gate math + state in registers -> scatter h into next B-frag buffer
//   -> ONE raw barrier (lgkmcnt only; vmcnt never drained -> gx prefetch
//      loads + h stores ride across steps).
__global__ __launch_bounds__(512, 1) void scan_kernel(
    const u16* __restrict__ gx4,   // [B][Tc][1024][4] bf16 preacts (nh,gate)
    const u16* __restrict__ RQ,    // [8][512][128] bf16, rows m=e*4+g
    const float* __restrict__ rb4, // [1024][4] recurrent biases interleaved
    float* __restrict__ state,     // [64][128][4] float c,n,m,h
    u16* __restrict__ hraw,        // [M][H] bf16 raw h
    int t0, int Tc, int init)
{
    const int blk = blockIdx.x;           // 0..63
    const int b = blk >> 3, hd = blk & 7;
    const int tid = threadIdx.x;
    const int w = tid >> 6, lane = tid & 63;
    const int lm = lane & 15, lq = lane >> 4;
    const int lane8 = lane * 8;
    const bool wr = (lm == 0);            // col-0 lanes own outputs + state

    // B-fragment double buffer, MFMA-linear: [buf][kc][lane][8 u16]
    __shared__ __align__(16) u16 hBf[2][2048];

    // preload A fragments: wave w owns rows 64w..64w+63
    bf16x8 a[4][4];
    const u16* RQh = RQ + (size_t)hd * (512 * 128);
#pragma unroll
    for (int i = 0; i < 4; ++i)
#pragma unroll
        for (int kc = 0; kc < 4; ++kc)
            a[i][kc] = *(const bf16x8*)(RQh +
                (size_t)(w * 64 + i * 16 + lm) * 128 + kc * 32 + lq * 8);

    // element indices owned by this lane (if wr) and their B-frag slots
    int ev[4], sl[4];
#pragma unroll
    for (int i = 0; i < 4; ++i) {
        ev[i] = (w << 4) | (i << 2) | lq;                       // e = 16w+4i+lq
        sl[i] = ((ev[i] >> 5) << 9) | (((ev[i] >> 3) & 3) << 7) | (ev[i] & 7);
    }

    float cS[4], nS[4], mS[4], hS[4];
    float4 rb[4];
    if (wr) {
#pragma unroll
        for (int i = 0; i < 4; ++i) {
            rb[i] = ((const float4*)rb4)[(hd << 7) + ev[i]];
            if (init) { cS[i] = 0.f; nS[i] = 1.f; mS[i] = 0.f; hS[i] = 0.f; }
            else {
                float4 s = ((const float4*)state)[(blk << 7) + ev[i]];
                cS[i] = s.x; nS[i] = s.y; mS[i] = s.z; hS[i] = s.w;
            }
        }
    }

    // zero both B-frag buffers (non-col-0 slots must stay 0 forever)
    for (int j = tid; j < 2048; j += 512) ((unsigned*)hBf)[j] = 0u;
    __syncthreads();
    if (wr) {
#pragma unroll
        for (int i = 0; i < 4; ++i) hBf[0][sl[i]] = f2b(hS[i]);
    }
    __syncthreads();

    const u16* gxb = gx4 + (size_t)b * Tc * 4096 + (hd << 9);
    u16* hout = hraw + (size_t)(b * T_ + t0) * H_ + (hd << 7);

    // prefetch gate preacts for steps 0 and 1 (ushort4 = z,i,o,f per e)
    ushort4 pA[4], pB[4];
    if (wr) {
        const ushort4* g0 = (const ushort4*)gxb;
        const ushort4* g1 = (const ushort4*)(gxb + 4096);
#pragma unroll
        for (int i = 0; i < 4; ++i) { pA[i] = g0[ev[i]]; pB[i] = g1[ev[i]]; }
    }

#define SCAN_STEP(TL, RB, WB, PF)                                              \
    {                                                                          \
        v4f acc[4];                                                            \
        _Pragma("unroll") for (int i = 0; i < 4; ++i)                          \
            _Pragma("unroll") for (int r = 0; r < 4; ++r) acc[i][r] = 0.f;     \
        _Pragma("unroll") for (int kc = 0; kc < 4; ++kc) {                     \
            bf16x8 bv = *(const bf16x8*)(&hBf[RB][kc * 512 + lane8]);          \
            _Pragma("unroll") for (int i = 0; i < 4; ++i)                      \
                acc[i] = __builtin_amdgcn_mfma_f32_16x16x32_bf16(              \
                    a[i][kc], bv, acc[i], 0, 0, 0);                            \
        }                                                                      \
        if (wr) {                                                              \
            const int tn = ((TL) + 2 < Tc) ? (TL) + 2 : Tc - 1;                \
            const ushort4* gn = (const ushort4*)(gxb + (size_t)tn * 4096);     \
            float gv[4][4];                                                    \
            _Pragma("unroll") for (int i = 0; i < 4; ++i) {                    \
                gv[i][0] = b2f(PF[i].x); gv[i][1] = b2f(PF[i].y);              \
                gv[i][2] = b2f(PF[i].z); gv[i][3] = b2f(PF[i].w);              \
            }                                                                  \
            _Pragma("unroll") for (int i = 0; i < 4; ++i) PF[i] = gn[ev[i]];   \
            _Pragma("unroll") for (int i = 0; i < 4; ++i) {                    \
                const float zp = acc[i][0] + gv[i][0] + rb[i].x;               \
                const float ip = softcap15(acc[i][1] + gv[i][1] + rb[i].y);    \
                const float op = acc[i][2] + gv[i][2] + rb[i].z;               \
                const float fp = softcap15(acc[i][3] + gv[i][3] + rb[i].w);    \
                const float zv = ftanh(zp);                                    \
                const float ov = __builtin_amdgcn_rcpf(1.f + __expf(-op));     \
                const float mt = fmaxf(fp + mS[i], ip);                        \
                const float ig = __expf(ip - mt);                              \
                const float fg = __expf(fp - mt + mS[i]);                      \
                cS[i] = fg * cS[i] + ig * zv;                                  \
                nS[i] = fg * nS[i] + ig;                                       \
                mS[i] = mt;                                                    \
                const float hv = ov * cS[i] *                                  \
                    __builtin_amdgcn_rcpf(fmaxf(nS[i], 1.f));                  \
                hS[i] = hv;                                                    \
                const u16 hb = f2b(hv);                                        \
                hBf[WB][sl[i]] = hb;                                           \
                hout[(size_t)(TL) * H_ + ev[i]] = hb;                          \
            }                                                                  \
        }                                                                      \
        asm volatile("s_waitcnt lgkmcnt(0)" ::: "memory");                     \
        __builtin_amdgcn_s_barrier();                                          \
        asm volatile("" ::: "memory");                                         \
    }

    for (int tl = 0; tl < Tc; tl += 2) {
        SCAN_STEP(tl,     0, 1, pA)
        SCAN_STEP(tl + 1, 1, 0, pB)
    }
#undef SCAN_STEP

    if (wr) {
#pragma unroll
        for (int i = 0; i < 4; ++i)
            ((float4*)state)[(blk << 7) + ev[i]] =
                make_float4(cS[i], nS[i], mS[i], hS[i]);
    }
}

// ---------------- multihead layernorm (in-place capable) --------------------
__global__ __launch_bounds__(512) void mln_kernel(
    const u16* __restrict__ h_all, const float* __restrict__ w,
    const float* __restrict__ b, u16* __restrict__ hb)
{
    const int token = blockIdx.x, tid = threadIdx.x;
    const int wave = tid >> 6, lane = tid & 63;
    const u16* hr = h_all + (size_t)token * H_ + wave * DH_;
    float a0 = b2f(hr[lane]), a1 = b2f(hr[64 + lane]);
    float s = a0 + a1, ss = a0 * a0 + a1 * a1;
    for (int off = 32; off; off >>= 1) { s += __shfl_xor(s, off); ss += __shfl_xor(ss, off); }
    const float mu = s * (1.f / 128.f);
    const float var = ss * (1.f / 128.f) - mu * mu;
    const float rs = rsqrtf(var + 1e-6f);
    const int c0 = wave * DH_ + lane;
    u16* hw = hb + (size_t)token * H_ + wave * DH_;
    hw[lane]      = f2b((a0 - mu) * rs * w[c0] + b[c0]);
    hw[64 + lane] = f2b((a1 - mu) * rs * w[c0 + 64] + b[c0 + 64]);
}

// ---------------- up-GEMM with fused GEGLU ----------------------------------
__global__ __launch_bounds__(256) void gemm_up_geglu(
    const u16* __restrict__ A, const u16* __restrict__ B1T,
    const u16* __restrict__ B2T, const float* __restrict__ upb,
    u16* __restrict__ G)
{
    __shared__ __align__(16) u16 As[4096], B1s[4096], B2s[4096];
    v4f acc1[4][4], acc2[4][4];
#pragma unroll
    for (int i = 0; i < 4; ++i)
#pragma unroll
        for (int j = 0; j < 4; ++j)
#pragma unroll
            for (int r = 0; r < 4; ++r) { acc1[i][j][r] = 0.f; acc2[i][j][r] = 0.f; }
    const int m0 = blockIdx.y * 128, n0 = blockIdx.x * 128;
    const int tid = threadIdx.x;
    const int wave = tid >> 6, lane = tid & 63;
    const int wm = wave & 1, wn = wave >> 1;
    const int srow = tid >> 2, sseg = tid & 3;
    const int lm = lane & 15, lq = lane >> 4;

    const u16* gA0 = A   + (size_t)(m0 + srow) * H_ + sseg * 8;
    const u16* gA1 = gA0 + (size_t)64 * H_;
    const u16* g10 = B1T + (size_t)(n0 + srow) * H_ + sseg * 8;
    const u16* g11 = g10 + (size_t)64 * H_;
    const u16* g20 = B2T + (size_t)(n0 + srow) * H_ + sseg * 8;
    const u16* g21 = g20 + (size_t)64 * H_;
    u16* lA0 = As  + wave * 512;        u16* lA1 = As  + 2048 + wave * 512;
    u16* l10 = B1s + wave * 512;        u16* l11 = B1s + 2048 + wave * 512;
    u16* l20 = B2s + wave * 512;        u16* l21 = B2s + 2048 + wave * 512;

    for (int kk = 0; kk < H_; kk += 32) {
        GLD16(gA0 + kk, lA0); GLD16(gA1 + kk, lA1);
        GLD16(g10 + kk, l10); GLD16(g11 + kk, l11);
        GLD16(g20 + kk, l20); GLD16(g21 + kk, l21);
        __syncthreads();
        bf16x8 a[4], b1[4], b2[4];
#pragma unroll
        for (int i = 0; i < 4; ++i) {
            a[i]  = *(const bf16x8*)(As  + (wm * 64 + i * 16 + lm) * 32 + lq * 8);
            b1[i] = *(const bf16x8*)(B1s + (wn * 64 + i * 16 + lm) * 32 + lq * 8);
            b2[i] = *(const bf16x8*)(B2s + (wn * 64 + i * 16 + lm) * 32 + lq * 8);
        }
#pragma unroll
        for (int i = 0; i < 4; ++i)
#pragma unroll
            for (int j = 0; j < 4; ++j) {
                acc1[i][j] = __builtin_amdgcn_mfma_f32_16x16x32_bf16(a[i], b1[j], acc1[i][j], 0, 0, 0);
                acc2[i][j] = __builtin_amdgcn_mfma_f32_16x16x32_bf16(a[i], b2[j], acc2[i][j], 0, 0, 0);
            }
        __syncthreads();
    }
    const int col = lane & 15, rb0 = (lane >> 4) * 4;
#pragma unroll
    for (int j = 0; j < 4; ++j) {
        const int n = n0 + wn * 64 + j * 16 + col;
        const bool ok = (n < P_);
        const float bb1 = ok ? upb[n] : 0.f;
        const float bb2 = ok ? upb[P_ + n] : 0.f;
#pragma unroll
        for (int i = 0; i < 4; ++i)
#pragma unroll
            for (int r = 0; r < 4; ++r) {
                const int mm = m0 + wm * 64 + i * 16 + rb0 + r;
                float gval = 0.f;
                if (ok) {
                    const float u1 = acc1[i][j][r] + bb1;
                    const float u2 = acc2[i][j][r] + bb2;
                    const float ge = 0.5f * u2 * (1.f + erff(u2 * 0.70710678118654752f));
                    gval = u1 * ge;
                }
                G[(size_t)mm * PPAD_ + n] = f2b(gval);
            }
    }
}

// ---------------- down GEMM -> fp32 out with bias + residual ----------------
__global__ __launch_bounds__(256) void gemm_down_out(
    const u16* __restrict__ A, const u16* __restrict__ BT,
    const float* __restrict__ bias, const float* __restrict__ resid,
    float* __restrict__ C, int K, int ldc)
{
    v4f acc[4][4];
#pragma unroll
    for (int i = 0; i < 4; ++i)
#pragma unroll
        for (int j = 0; j < 4; ++j)
#pragma unroll
            for (int r = 0; r < 4; ++r) acc[i][j][r] = 0.f;
    const int m0 = blockIdx.y * 128, n0 = blockIdx.x * 128;
    gemm128_core(A, BT, K, m0, n0, acc);
    const int tid = threadIdx.x, wave = tid >> 6, lane = tid & 63;
    const int wm = wave & 1, wn = wave >> 1;
    const int col = lane & 15, rb0 = (lane >> 4) * 4;
#pragma unroll
    for (int j = 0; j < 4; ++j) {
        const int n = n0 + wn * 64 + j * 16 + col;
        const float bv = bias[n];
#pragma unroll
        for (int i = 0; i < 4; ++i)
#pragma unroll
            for (int r = 0; r < 4; ++r) {
                const int mm = m0 + wm * 64 + i * 16 + rb0 + r;
                C[(size_t)mm * ldc + n] = acc[i][j][r] + bv + resid[(size_t)mm * ldc + n];
            }
    }
}

// ============================ launcher ======================================
extern "C" void kernel_launch(void* const* d_in, const int* in_sizes, int n_in,
                              void* d_out, int out_size, void* d_ws, size_t ws_size,
                              hipStream_t stream)
{
    const float* x     = (const float*)d_in[0];
    const float* ln_w  = (const float*)d_in[1];
    const float* ln_b  = (const float*)d_in[2];
    const float* hln_w = (const float*)d_in[3];
    const float* hln_b = (const float*)d_in[4];
    const float* Wz = (const float*)d_in[5];  const float* bz  = (const float*)d_in[6];
    const float* Wi = (const float*)d_in[7];  const float* bi  = (const float*)d_in[8];
    const float* Wo = (const float*)d_in[9];  const float* bo  = (const float*)d_in[10];
    const float* Wf = (const float*)d_in[11]; const float* bfv = (const float*)d_in[12];
    const float* Rz = (const float*)d_in[13]; const float* rbz = (const float*)d_in[14];
    const float* Ri = (const float*)d_in[15]; const float* rbi = (const float*)d_in[16];
    const float* Ro = (const float*)d_in[17]; const float* rbo = (const float*)d_in[18];
    const float* Rf = (const float*)d_in[19]; const float* rbf = (const float*)d_in[20];
    const float* up_w   = (const float*)d_in[21]; const float* up_b   = (const float*)d_in[22];
    const float* down_w = (const float*)d_in[23]; const float* down_b = (const float*)d_in[24];
    float* out = (float*)d_out;

    // ---- workspace layout (adaptive to ws_size) ----
    size_t off = 0;
    char* base = (char*)d_ws;
    auto alloc = [&](size_t bytes) -> char* {
        char* r = base + off; off += (bytes + 255) & ~(size_t)255; return r;
    };
    u16*   WT4   = (u16*)  alloc((size_t)4 * H_ * D_ * 2);      // 8 MiB (interleaved cols)
    u16*   W1T   = (u16*)  alloc((size_t)PPAD_ * H_ * 2);       // 2.75 MiB
    u16*   W2T   = (u16*)  alloc((size_t)PPAD_ * H_ * 2);       // 2.75 MiB
    u16*   dnT   = (u16*)  alloc((size_t)D_ * PPAD_ * 2);       // 2.75 MiB
    u16*   RQ    = (u16*)  alloc((size_t)8 * 512 * 128 * 2);    // 1 MiB
    float* bias4 = (float*)alloc(4096 * 4);
    float* rb4   = (float*)alloc(4096 * 4);
    float* state = (float*)alloc((size_t)64 * 4 * 128 * 4);     // 128 KiB
    u16*   hbn   = (u16*)  alloc((size_t)M_ * H_ * 2);          // 32 MiB
    char*  dyn   = base + off;
    u16*   xnb   = (u16*)dyn;                                   // 32 MiB
    const size_t xnb_bytes = (size_t)M_ * H_ * 2;
    u16*   gbuf  = (u16*)dyn;  // overlays xnb+gx (both dead by up-GEMM time)

    // pick largest Tc whose gx chunk fits
    const size_t fixed = off + xnb_bytes;
    int Tc = 256;
    if      (ws_size >= fixed + (size_t)4 * B_ * 2048 * H_ * 2) Tc = 2048;
    else if (ws_size >= fixed + (size_t)4 * B_ * 1024 * H_ * 2) Tc = 1024;
    else if (ws_size >= fixed + (size_t)4 * B_ * 512  * H_ * 2) Tc = 512;
    u16* gx = (u16*)(dyn + xnb_bytes);
    const int NC = T_ / Tc;

    // ---- weight prep ----
    dim3 tb(32, 8);
    const float* Ws[4] = {Wz, Wi, Wo, Wf};
    for (int g = 0; g < 4; ++g)
        transpose_cast<<<dim3(32, 32), tb, 0, stream>>>(
            Ws[g], WT4, D_, H_, D_, H_, H_, 4, g);   // col-interleaved rows nh*4+g
    transpose_cast<<<dim3(44, 32), tb, 0, stream>>>(up_w,      W1T, H_, P_, H_, PPAD_, 2 * P_, 1, 0);
    transpose_cast<<<dim3(44, 32), tb, 0, stream>>>(up_w + P_, W2T, H_, P_, H_, PPAD_, 2 * P_, 1, 0);
    transpose_cast<<<dim3(32, 44), tb, 0, stream>>>(down_w, dnT, P_, D_, PPAD_, D_, D_, 1, 0);
    bias4_concat<<<16, 256, 0, stream>>>(bz, bi, bo, bfv, bias4);
    bias4_concat<<<16, 256, 0, stream>>>(rbz, rbi, rbo, rbf, rb4);
    rq_prep<<<dim3(512, 8), 128, 0, stream>>>(Rz, Ri, Ro, Rf, RQ);

    // ---- input LN ----
    ln_cast_kernel<<<M_, 256, 0, stream>>>(x, ln_w, ln_b, xnb);

    // ---- chunked gate GEMM + scan ----
    for (int cidx = 0; cidx < NC; ++cidx) {
        const int t0 = cidx * Tc;
        gemm_gate4<<<dim3(32, B_ * (Tc / 128)), 256, 0, stream>>>(
            xnb, WT4, bias4, gx, t0, Tc);
        scan_kernel<<<64, 512, 0, stream>>>(
            gx, RQ, rb4, state, hbn, t0, Tc, cidx == 0 ? 1 : 0);
    }

    // ---- multihead LN (in place) ----
    mln_kernel<<<M_, 512, 0, stream>>>(hbn, hln_w, hln_b, hbn);

    // ---- FFN ----
    gemm_up_geglu<<<dim3(PPAD_ / 128, 128), 256, 0, stream>>>(hbn, W1T, W2T, up_b, gbuf);
    gemm_down_out<<<dim3(8, 128), 256, 0, stream>>>(gbuf, dnT, down_b, x, out, PPAD_, D_);

    (void)in_sizes; (void)n_in; (void)out_size;
}

// Round 2
// 2052.873 us; speedup vs baseline: 1.5842x; 1.5842x over previous
//
#include <hip/hip_runtime.h>

typedef unsigned short u16;
typedef __attribute__((ext_vector_type(4))) float v4f;
typedef __attribute__((ext_vector_type(8))) short bf16x8;

#define B_ 8
#define T_ 2048
#define D_ 1024
#define NH_ 8
#define DH_ 128
#define H_ 1024
#define P_ 1365
#define PPAD_ 1408   // P padded to multiple of 128 (up-GEMM N, down-GEMM K)
#define M_ 16384     // B*T

// ---------- bf16 helpers (manual RNE) ---------------------------------------
__device__ __forceinline__ u16 f2b(float f) {
    union { float f; unsigned u; } v; v.f = f;
    unsigned r = (v.u + 0x7fffu + ((v.u >> 16) & 1u)) >> 16;
    return (u16)r;
}
__device__ __forceinline__ float b2f(u16 u) {
    union { unsigned u; float f; } v; v.u = ((unsigned)u) << 16;
    return v.f;
}

// quad broadcast: every lane gets quad-lane S's value (full-rate DPP mov)
template<int S>
__device__ __forceinline__ float qb(float x) {
    return __int_as_float(__builtin_amdgcn_update_dpp(
        0, __float_as_int(x), S * 0x55, 0xF, 0xF, true));
}

// async global->LDS, 16B per lane; lds ptr must be wave-uniform
#define GLD16(gp, lp) __builtin_amdgcn_global_load_lds( \
    (const __attribute__((address_space(1))) void*)(gp), \
    (__attribute__((address_space(3))) void*)(lp), 16, 0, 0)

// ---------------- transpose + cast fp32 -> bf16 ------------------------------
// output row index = n*rowmul + rowoff (lets the 4 gate weights interleave
// their columns: WT4i[nh*4+g][k], so gate-GEMM output is [t][nh][g] packed)
__global__ __launch_bounds__(256) void transpose_cast(
    const float* __restrict__ in, u16* __restrict__ out,
    int K, int N, int Kpad, int Npad, int ldin, int rowmul, int rowoff)
{
    __shared__ float tile[32][33];
    const int tx = threadIdx.x, ty = threadIdx.y;
    const int nblk = blockIdx.x * 32, kblk = blockIdx.y * 32;
#pragma unroll
    for (int i = 0; i < 4; ++i) {
        int k = kblk + ty + i * 8, n = nblk + tx;
        float v = (k < K && n < N) ? in[(size_t)k * ldin + n] : 0.f;
        tile[ty + i * 8][tx] = v;
    }
    __syncthreads();
#pragma unroll
    for (int i = 0; i < 4; ++i) {
        int n = nblk + ty + i * 8, k = kblk + tx;
        if (n < Npad && k < Kpad)
            out[((size_t)n * rowmul + rowoff) * Kpad + k] = f2b(tile[tx][ty + i * 8]);
    }
}

// ---------------- concat 4 per-gate vectors [1024] -> interleaved [1024][4] -
__global__ __launch_bounds__(256) void bias4_concat(
    const float* __restrict__ bz, const float* __restrict__ bi,
    const float* __restrict__ bo, const float* __restrict__ bf,
    float* __restrict__ b4)
{
    int j = blockIdx.x * 256 + threadIdx.x;  // 0..4095
    const float* p = (j < 1024) ? bz : (j < 2048) ? bi : (j < 3072) ? bo : bf;
    b4[((j & 1023) << 2) | (j >> 10)] = p[j & 1023];
}

// ---------------- pack R into MFMA A-layout: RQ[hd][m=e*4+g][d] bf16 --------
__global__ __launch_bounds__(128) void rq_prep(
    const float* __restrict__ Rz, const float* __restrict__ Ri,
    const float* __restrict__ Ro, const float* __restrict__ Rf,
    u16* __restrict__ RQ)
{
    const int m = blockIdx.x;      // 0..511
    const int hd = blockIdx.y;     // 0..7
    const int d = threadIdx.x;     // 0..127
    const int g = m & 3, e = m >> 2;
    const float* Rg = (g == 0) ? Rz : (g == 1) ? Ri : (g == 2) ? Ro : Rf;
    RQ[((size_t)hd * 512 + m) * 128 + d] =
        f2b(Rg[((size_t)hd * 128 + d) * 128 + e]);
}

// ---------------- LayerNorm over D=1024 + cast to bf16 ----------------------
__global__ __launch_bounds__(256) void ln_cast_kernel(
    const float* __restrict__ x, const float* __restrict__ w,
    const float* __restrict__ b, u16* __restrict__ xnb)
{
    const int token = blockIdx.x, tid = threadIdx.x;
    const float4* xr = (const float4*)(x + (size_t)token * D_);
    float4 v = xr[tid];
    float s  = v.x + v.y + v.z + v.w;
    float ss = v.x * v.x + v.y * v.y + v.z * v.z + v.w * v.w;
    for (int off = 32; off; off >>= 1) { s += __shfl_down(s, off); ss += __shfl_down(ss, off); }
    __shared__ float wsum[4], wsq[4], stats[2];
    const int wave = tid >> 6, lane = tid & 63;
    if (lane == 0) { wsum[wave] = s; wsq[wave] = ss; }
    __syncthreads();
    if (tid == 0) {
        float S = 0.f, SS = 0.f;
        for (int i = 0; i < 4; ++i) { S += wsum[i]; SS += wsq[i]; }
        float mu = S * (1.f / 1024.f);
        float var = SS * (1.f / 1024.f) - mu * mu;
        stats[0] = mu; stats[1] = rsqrtf(var + 1e-6f);
    }
    __syncthreads();
    const float mu = stats[0], rs = stats[1];
    float4 wv = ((const float4*)w)[tid];
    float4 bv = ((const float4*)b)[tid];
    ushort4 o;
    o.x = f2b((v.x - mu) * rs * wv.x + bv.x);
    o.y = f2b((v.y - mu) * rs * wv.y + bv.y);
    o.z = f2b((v.z - mu) * rs * wv.z + bv.z);
    o.w = f2b((v.w - mu) * rs * wv.w + bv.w);
    ((ushort4*)(xnb + (size_t)token * D_))[tid] = o;
}

// ---------------- m97-style bf16 MFMA GEMM core (128x128 tile, BK=32) -------
__device__ __forceinline__ void gemm128_core(
    const u16* __restrict__ A, const u16* __restrict__ BT,
    int K, int m0, int n0, v4f acc[4][4])
{
    __shared__ __align__(16) u16 As[4096];  // [128][32]
    __shared__ __align__(16) u16 Bs[4096];  // [128][32]
    const int tid = threadIdx.x;
    const int wave = tid >> 6, lane = tid & 63;
    const int wm = wave & 1, wn = wave >> 1;
    const int srow = tid >> 2, sseg = tid & 3;
    const int lm = lane & 15, lq = lane >> 4;

    const u16* gA0 = A  + (size_t)(m0 + srow) * K + sseg * 8;
    const u16* gA1 = gA0 + (size_t)64 * K;
    const u16* gB0 = BT + (size_t)(n0 + srow) * K + sseg * 8;
    const u16* gB1 = gB0 + (size_t)64 * K;
    u16* lA0 = As + wave * 512;
    u16* lA1 = As + 2048 + wave * 512;
    u16* lB0 = Bs + wave * 512;
    u16* lB1 = Bs + 2048 + wave * 512;

    for (int kk = 0; kk < K; kk += 32) {
        GLD16(gA0 + kk, lA0);
        GLD16(gA1 + kk, lA1);
        GLD16(gB0 + kk, lB0);
        GLD16(gB1 + kk, lB1);
        __syncthreads();
        bf16x8 a[4], b[4];
#pragma unroll
        for (int i = 0; i < 4; ++i) {
            a[i] = *(const bf16x8*)(As + (wm * 64 + i * 16 + lm) * 32 + lq * 8);
            b[i] = *(const bf16x8*)(Bs + (wn * 64 + i * 16 + lm) * 32 + lq * 8);
        }
#pragma unroll
        for (int i = 0; i < 4; ++i)
#pragma unroll
            for (int j = 0; j < 4; ++j)
                acc[i][j] = __builtin_amdgcn_mfma_f32_16x16x32_bf16(a[i], b[j], acc[i][j], 0, 0, 0);
        __syncthreads();
    }
}

// ---------------- fused 4-gate GEMM (N=4096, cols = nh*4+g interleaved) -----
__global__ __launch_bounds__(256) void gemm_gate4(
    const u16* __restrict__ A, const u16* __restrict__ WT4,
    const float* __restrict__ bias4, u16* __restrict__ gx4,
    int t0, int Tc)
{
    v4f acc[4][4];
#pragma unroll
    for (int i = 0; i < 4; ++i)
#pragma unroll
        for (int j = 0; j < 4; ++j)
#pragma unroll
            for (int r = 0; r < 4; ++r) acc[i][j][r] = 0.f;
    const int mtPerB = Tc >> 7;
    const int b_ = blockIdx.y / mtPerB, tt = blockIdx.y % mtPerB;
    const int m0 = b_ * T_ + t0 + tt * 128;
    const int n0 = blockIdx.x * 128;
    gemm128_core(A, WT4, D_, m0, n0, acc);
    const int r0 = b_ * Tc + tt * 128;   // row in chunk space
    const int tid = threadIdx.x, wave = tid >> 6, lane = tid & 63;
    const int wm = wave & 1, wn = wave >> 1;
    const int col = lane & 15, rb0 = (lane >> 4) * 4;
#pragma unroll
    for (int j = 0; j < 4; ++j) {
        const int n = n0 + wn * 64 + j * 16 + col;
        const float bv = bias4[n];
#pragma unroll
        for (int i = 0; i < 4; ++i)
#pragma unroll
            for (int r = 0; r < 4; ++r) {
                const int rr = r0 + wm * 64 + i * 16 + rb0 + r;
                gx4[(size_t)rr * 4096 + n] = f2b(acc[i][j][r] + bv);
            }
    }
}

// ---------------- MFMA sequential scan, all-lane gate math ------------------
// One WG per (batch, head). 512 thr = 8 waves. Per step:
//   ds_read B-frag (conflict-free) -> 16 MFMA (8 indep 2-chains) ->
//   col-0 lanes stage acc to per-wave LDS (same-wave, NO barrier) ->
//   all 64 lanes: lane l = gate (l&3) of element (l>>2): uniform 1-exp
//   transform K0 - K1*rcp(exp(K2*x)+1) -> DPP quad-bcast -> g==0 lanes
//   update state in regs (single exp for ig/fg) -> scatter h to next B-frag
//   -> ONE lgkm-only barrier (vmcnt never drained; gx prefetch depth 4).
__global__ __launch_bounds__(512, 1) void scan_kernel(
    const u16* __restrict__ gx4,   // [B][Tc][4096] bf16, idx hd*512+e*4+g
    const u16* __restrict__ RQ,    // [8][512][128] bf16, rows m=e*4+g
    const float* __restrict__ rb4, // [1024][4] recurrent biases interleaved
    float* __restrict__ state,     // [64][128] float4 c,n,m,h
    u16* __restrict__ hraw,        // [M][H] bf16 raw h
    int t0, int Tc, int init)
{
    const int blk = blockIdx.x;           // 0..63
    const int b = blk >> 3, hd = blk & 7;
    const int tid = threadIdx.x;
    const int w = tid >> 6, lane = tid & 63;
    const int lm = lane & 15, lq = lane >> 4;
    const int lane8 = lane * 8;
    const int g = lane & 3;               // gate handled by this lane
    const int e = (w << 4) + (lane >> 2); // element handled by this lane
    const bool st_lane = (g == 0);        // state-owning lanes (16 per wave)

    // B-fragment double buffer, MFMA-linear: [buf][kc][lane][8 u16]
    __shared__ __align__(16) u16 hBf[2][2048];
    // per-wave matvec staging: [w][el][g] float (same-wave redistribution)
    __shared__ __align__(16) float stg[512];

    // preload A fragments: wave w owns rows 64w..64w+63
    bf16x8 a[4][4];
    const u16* RQh = RQ + (size_t)hd * (512 * 128);
#pragma unroll
    for (int i = 0; i < 4; ++i)
#pragma unroll
        for (int kc = 0; kc < 4; ++kc)
            a[i][kc] = *(const bf16x8*)(RQh +
                (size_t)(w * 64 + i * 16 + lm) * 128 + kc * 32 + lq * 8);

    // per-lane gate constants: tanh / 15*tanh(./15) / sigmoid, all as
    //   K0 - K1 * rcp(exp(K2*x) + 1)
    const float K0 = (g == 1 || g == 3) ? 15.f : 1.f;
    const float K1 = (g == 0) ? 2.f : (g == 2) ? 1.f : 30.f;
    const float K2 = (g == 0) ? 2.f : (g == 2) ? 1.f : (2.f / 15.f);
    const float rb_l = rb4[(hd << 9) + (w << 6) + lane];

    // state in registers of st_lanes
    float cS = 0.f, nS = 1.f, mS = 0.f, hS = 0.f;
    if (st_lane && !init) {
        float4 s = ((const float4*)state)[(blk << 7) + e];
        cS = s.x; nS = s.y; mS = s.z; hS = s.w;
    }
    // B-frag slot for element e (K=32 chunks, quad q, sub j)
    const int sl = ((e >> 5) << 9) | (((e >> 3) & 3) << 7) | (e & 7);

    // zero both B-frag buffers (non-col-0 slots must stay 0 forever)
    for (int j = tid; j < 2048; j += 512) ((unsigned*)hBf)[j] = 0u;
    __syncthreads();
    if (st_lane) hBf[0][sl] = f2b(hS);
    __syncthreads();

    const u16* gxb = gx4 + (size_t)b * Tc * 4096 + (hd << 9) + (w << 6) + lane;
    u16* houtp = hraw + (size_t)(b * T_ + t0) * H_ + (hd << 7) + e;

    // prefetch gate preacts depth 4 (1 u16 per lane per step, coalesced)
    u16 pgA = gxb[0], pgB = gxb[4096], pgC = gxb[2 * 4096], pgD = gxb[3 * 4096];

#define SCAN_STEP(TL, RB, WB, PG)                                              \
    {                                                                          \
        v4f p0[4], p1[4];                                                      \
        _Pragma("unroll") for (int i = 0; i < 4; ++i)                          \
            _Pragma("unroll") for (int r = 0; r < 4; ++r) {                    \
                p0[i][r] = 0.f; p1[i][r] = 0.f; }                              \
        const bf16x8 bv0 = *(const bf16x8*)(&hBf[RB][0 * 512 + lane8]);        \
        const bf16x8 bv1 = *(const bf16x8*)(&hBf[RB][1 * 512 + lane8]);        \
        const bf16x8 bv2 = *(const bf16x8*)(&hBf[RB][2 * 512 + lane8]);        \
        const bf16x8 bv3 = *(const bf16x8*)(&hBf[RB][3 * 512 + lane8]);        \
        _Pragma("unroll") for (int i = 0; i < 4; ++i) {                        \
            p0[i] = __builtin_amdgcn_mfma_f32_16x16x32_bf16(a[i][0], bv0, p0[i], 0, 0, 0); \
            p1[i] = __builtin_amdgcn_mfma_f32_16x16x32_bf16(a[i][1], bv1, p1[i], 0, 0, 0); \
            p0[i] = __builtin_amdgcn_mfma_f32_16x16x32_bf16(a[i][2], bv2, p0[i], 0, 0, 0); \
            p1[i] = __builtin_amdgcn_mfma_f32_16x16x32_bf16(a[i][3], bv3, p1[i], 0, 0, 0); \
        }                                                                      \
        if (lm == 0) {                                                         \
            _Pragma("unroll") for (int i = 0; i < 4; ++i)                      \
                *(v4f*)(&stg[(w << 6) + (((i << 2) | lq) << 2)]) = p0[i] + p1[i]; \
        }                                                                      \
        asm volatile("s_waitcnt lgkmcnt(0)" ::: "memory");                     \
        __builtin_amdgcn_sched_barrier(0);                                     \
        const float matv = stg[(w << 6) + lane];                               \
        const int tn = ((TL) + 4 < Tc) ? (TL) + 4 : Tc - 1;                    \
        const u16 pgn = gxb[(size_t)tn * 4096];                                \
        const float pre = matv + b2f(PG) + rb_l;                               \
        PG = pgn;                                                              \
        const float tt = K0 - K1 * __builtin_amdgcn_rcpf(__expf(pre * K2) + 1.f); \
        const float ipv = qb<1>(tt);                                           \
        const float ovv = qb<2>(tt);                                           \
        const float fpv = qb<3>(tt);                                           \
        if (st_lane) {                                                         \
            const float bm = fpv + mS;                                         \
            const float d  = ipv - bm;                                         \
            const float mt = fmaxf(bm, ipv);                                   \
            const float e1 = __expf(-fabsf(d));                                \
            const float ig = (d >= 0.f) ? 1.f : e1;                            \
            const float fg = (d >= 0.f) ? e1 : 1.f;                            \
            cS = fg * cS + ig * tt;                                            \
            nS = fg * nS + ig;                                                 \
            mS = mt;                                                           \
            const float hv = ovv * cS * __builtin_amdgcn_rcpf(fmaxf(nS, 1.f)); \
            hS = hv;                                                           \
            const u16 hb = f2b(hv);                                            \
            hBf[WB][sl] = hb;                                                  \
            houtp[(size_t)(TL) * H_] = hb;                                     \
        }                                                                      \
        asm volatile("s_waitcnt lgkmcnt(0)" ::: "memory");                     \
        __builtin_amdgcn_s_barrier();                                          \
        __builtin_amdgcn_sched_barrier(0);                                     \
    }

    for (int tl = 0; tl < Tc; tl += 4) {
        SCAN_STEP(tl,     0, 1, pgA)
        SCAN_STEP(tl + 1, 1, 0, pgB)
        SCAN_STEP(tl + 2, 0, 1, pgC)
        SCAN_STEP(tl + 3, 1, 0, pgD)
    }
#undef SCAN_STEP

    if (st_lane) {
        ((float4*)state)[(blk << 7) + e] = make_float4(cS, nS, mS, hS);
    }
}

// ---------------- multihead layernorm (in-place capable) --------------------
__global__ __launch_bounds__(512) void mln_kernel(
    const u16* __restrict__ h_all, const float* __restrict__ w,
    const float* __restrict__ b, u16* __restrict__ hb)
{
    const int token = blockIdx.x, tid = threadIdx.x;
    const int wave = tid >> 6, lane = tid & 63;
    const u16* hr = h_all + (size_t)token * H_ + wave * DH_;
    float a0 = b2f(hr[lane]), a1 = b2f(hr[64 + lane]);
    float s = a0 + a1, ss = a0 * a0 + a1 * a1;
    for (int off = 32; off; off >>= 1) { s += __shfl_xor(s, off); ss += __shfl_xor(ss, off); }
    const float mu = s * (1.f / 128.f);
    const float var = ss * (1.f / 128.f) - mu * mu;
    const float rs = rsqrtf(var + 1e-6f);
    const int c0 = wave * DH_ + lane;
    u16* hw = hb + (size_t)token * H_ + wave * DH_;
    hw[lane]      = f2b((a0 - mu) * rs * w[c0] + b[c0]);
    hw[64 + lane] = f2b((a1 - mu) * rs * w[c0 + 64] + b[c0 + 64]);
}

// ---------------- up-GEMM with fused GEGLU ----------------------------------
__global__ __launch_bounds__(256) void gemm_up_geglu(
    const u16* __restrict__ A, const u16* __restrict__ B1T,
    const u16* __restrict__ B2T, const float* __restrict__ upb,
    u16* __restrict__ G)
{
    __shared__ __align__(16) u16 As[4096], B1s[4096], B2s[4096];
    v4f acc1[4][4], acc2[4][4];
#pragma unroll
    for (int i = 0; i < 4; ++i)
#pragma unroll
        for (int j = 0; j < 4; ++j)
#pragma unroll
            for (int r = 0; r < 4; ++r) { acc1[i][j][r] = 0.f; acc2[i][j][r] = 0.f; }
    const int m0 = blockIdx.y * 128, n0 = blockIdx.x * 128;
    const int tid = threadIdx.x;
    const int wave = tid >> 6, lane = tid & 63;
    const int wm = wave & 1, wn = wave >> 1;
    const int srow = tid >> 2, sseg = tid & 3;
    const int lm = lane & 15, lq = lane >> 4;

    const u16* gA0 = A   + (size_t)(m0 + srow) * H_ + sseg * 8;
    const u16* gA1 = gA0 + (size_t)64 * H_;
    const u16* g10 = B1T + (size_t)(n0 + srow) * H_ + sseg * 8;
    const u16* g11 = g10 + (size_t)64 * H_;
    const u16* g20 = B2T + (size_t)(n0 + srow) * H_ + sseg * 8;
    const u16* g21 = g20 + (size_t)64 * H_;
    u16* lA0 = As  + wave * 512;        u16* lA1 = As  + 2048 + wave * 512;
    u16* l10 = B1s + wave * 512;        u16* l11 = B1s + 2048 + wave * 512;
    u16* l20 = B2s + wave * 512;        u16* l21 = B2s + 2048 + wave * 512;

    for (int kk = 0; kk < H_; kk += 32) {
        GLD16(gA0 + kk, lA0); GLD16(gA1 + kk, lA1);
        GLD16(g10 + kk, l10); GLD16(g11 + kk, l11);
        GLD16(g20 + kk, l20); GLD16(g21 + kk, l21);
        __syncthreads();
        bf16x8 a[4], b1[4], b2[4];
#pragma unroll
        for (int i = 0; i < 4; ++i) {
            a[i]  = *(const bf16x8*)(As  + (wm * 64 + i * 16 + lm) * 32 + lq * 8);
            b1[i] = *(const bf16x8*)(B1s + (wn * 64 + i * 16 + lm) * 32 + lq * 8);
            b2[i] = *(const bf16x8*)(B2s + (wn * 64 + i * 16 + lm) * 32 + lq * 8);
        }
#pragma unroll
        for (int i = 0; i < 4; ++i)
#pragma unroll
            for (int j = 0; j < 4; ++j) {
                acc1[i][j] = __builtin_amdgcn_mfma_f32_16x16x32_bf16(a[i], b1[j], acc1[i][j], 0, 0, 0);
                acc2[i][j] = __builtin_amdgcn_mfma_f32_16x16x32_bf16(a[i], b2[j], acc2[i][j], 0, 0, 0);
            }
        __syncthreads();
    }
    const int col = lane & 15, rb0 = (lane >> 4) * 4;
#pragma unroll
    for (int j = 0; j < 4; ++j) {
        const int n = n0 + wn * 64 + j * 16 + col;
        const bool ok = (n < P_);
        const float bb1 = ok ? upb[n] : 0.f;
        const float bb2 = ok ? upb[P_ + n] : 0.f;
#pragma unroll
        for (int i = 0; i < 4; ++i)
#pragma unroll
            for (int r = 0; r < 4; ++r) {
                const int mm = m0 + wm * 64 + i * 16 + rb0 + r;
                float gval = 0.f;
                if (ok) {
                    const float u1 = acc1[i][j][r] + bb1;
                    const float u2 = acc2[i][j][r] + bb2;
                    const float ge = 0.5f * u2 * (1.f + erff(u2 * 0.70710678118654752f));
                    gval = u1 * ge;
                }
                G[(size_t)mm * PPAD_ + n] = f2b(gval);
            }
    }
}

// ---------------- down GEMM -> fp32 out with bias + residual ----------------
__global__ __launch_bounds__(256) void gemm_down_out(
    const u16* __restrict__ A, const u16* __restrict__ BT,
    const float* __restrict__ bias, const float* __restrict__ resid,
    float* __restrict__ C, int K, int ldc)
{
    v4f acc[4][4];
#pragma unroll
    for (int i = 0; i < 4; ++i)
#pragma unroll
        for (int j = 0; j < 4; ++j)
#pragma unroll
            for (int r = 0; r < 4; ++r) acc[i][j][r] = 0.f;
    const int m0 = blockIdx.y * 128, n0 = blockIdx.x * 128;
    gemm128_core(A, BT, K, m0, n0, acc);
    const int tid = threadIdx.x, wave = tid >> 6, lane = tid & 63;
    const int wm = wave & 1, wn = wave >> 1;
    const int col = lane & 15, rb0 = (lane >> 4) * 4;
#pragma unroll
    for (int j = 0; j < 4; ++j) {
        const int n = n0 + wn * 64 + j * 16 + col;
        const float bv = bias[n];
#pragma unroll
        for (int i = 0; i < 4; ++i)
#pragma unroll
            for (int r = 0; r < 4; ++r) {
                const int mm = m0 + wm * 64 + i * 16 + rb0 + r;
                C[(size_t)mm * ldc + n] = acc[i][j][r] + bv + resid[(size_t)mm * ldc + n];
            }
    }
}

// ============================ launcher ======================================
extern "C" void kernel_launch(void* const* d_in, const int* in_sizes, int n_in,
                              void* d_out, int out_size, void* d_ws, size_t ws_size,
                              hipStream_t stream)
{
    const float* x     = (const float*)d_in[0];
    const float* ln_w  = (const float*)d_in[1];
    const float* ln_b  = (const float*)d_in[2];
    const float* hln_w = (const float*)d_in[3];
    const float* hln_b = (const float*)d_in[4];
    const float* Wz = (const float*)d_in[5];  const float* bz  = (const float*)d_in[6];
    const float* Wi = (const float*)d_in[7];  const float* bi  = (const float*)d_in[8];
    const float* Wo = (const float*)d_in[9];  const float* bo  = (const float*)d_in[10];
    const float* Wf = (const float*)d_in[11]; const float* bfv = (const float*)d_in[12];
    const float* Rz = (const float*)d_in[13]; const float* rbz = (const float*)d_in[14];
    const float* Ri = (const float*)d_in[15]; const float* rbi = (const float*)d_in[16];
    const float* Ro = (const float*)d_in[17]; const float* rbo = (const float*)d_in[18];
    const float* Rf = (const float*)d_in[19]; const float* rbf = (const float*)d_in[20];
    const float* up_w   = (const float*)d_in[21]; const float* up_b   = (const float*)d_in[22];
    const float* down_w = (const float*)d_in[23]; const float* down_b = (const float*)d_in[24];
    float* out = (float*)d_out;

    // ---- workspace layout (adaptive to ws_size) ----
    size_t off = 0;
    char* base = (char*)d_ws;
    auto alloc = [&](size_t bytes) -> char* {
        char* r = base + off; off += (bytes + 255) & ~(size_t)255; return r;
    };
    u16*   WT4   = (u16*)  alloc((size_t)4 * H_ * D_ * 2);      // 8 MiB (interleaved cols)
    u16*   W1T   = (u16*)  alloc((size_t)PPAD_ * H_ * 2);       // 2.75 MiB
    u16*   W2T   = (u16*)  alloc((size_t)PPAD_ * H_ * 2);       // 2.75 MiB
    u16*   dnT   = (u16*)  alloc((size_t)D_ * PPAD_ * 2);       // 2.75 MiB
    u16*   RQ    = (u16*)  alloc((size_t)8 * 512 * 128 * 2);    // 1 MiB
    float* bias4 = (float*)alloc(4096 * 4);
    float* rb4   = (float*)alloc(4096 * 4);
    float* state = (float*)alloc((size_t)64 * 4 * 128 * 4);     // 128 KiB
    u16*   hbn   = (u16*)  alloc((size_t)M_ * H_ * 2);          // 32 MiB
    char*  dyn   = base + off;
    u16*   xnb   = (u16*)dyn;                                   // 32 MiB
    const size_t xnb_bytes = (size_t)M_ * H_ * 2;
    u16*   gbuf  = (u16*)dyn;  // overlays xnb+gx (both dead by up-GEMM time)

    // pick largest Tc whose gx chunk fits
    const size_t fixed = off + xnb_bytes;
    int Tc = 256;
    if      (ws_size >= fixed + (size_t)4 * B_ * 2048 * H_ * 2) Tc = 2048;
    else if (ws_size >= fixed + (size_t)4 * B_ * 1024 * H_ * 2) Tc = 1024;
    else if (ws_size >= fixed + (size_t)4 * B_ * 512  * H_ * 2) Tc = 512;
    u16* gx = (u16*)(dyn + xnb_bytes);
    const int NC = T_ / Tc;

    // ---- weight prep ----
    dim3 tb(32, 8);
    const float* Ws[4] = {Wz, Wi, Wo, Wf};
    for (int g = 0; g < 4; ++g)
        transpose_cast<<<dim3(32, 32), tb, 0, stream>>>(
            Ws[g], WT4, D_, H_, D_, H_, H_, 4, g);   // col-interleaved rows nh*4+g
    transpose_cast<<<dim3(44, 32), tb, 0, stream>>>(up_w,      W1T, H_, P_, H_, PPAD_, 2 * P_, 1, 0);
    transpose_cast<<<dim3(44, 32), tb, 0, stream>>>(up_w + P_, W2T, H_, P_, H_, PPAD_, 2 * P_, 1, 0);
    transpose_cast<<<dim3(32, 44), tb, 0, stream>>>(down_w, dnT, P_, D_, PPAD_, D_, D_, 1, 0);
    bias4_concat<<<16, 256, 0, stream>>>(bz, bi, bo, bfv, bias4);
    bias4_concat<<<16, 256, 0, stream>>>(rbz, rbi, rbo, rbf, rb4);
    rq_prep<<<dim3(512, 8), 128, 0, stream>>>(Rz, Ri, Ro, Rf, RQ);

    // ---- input LN ----
    ln_cast_kernel<<<M_, 256, 0, stream>>>(x, ln_w, ln_b, xnb);

    // ---- chunked gate GEMM + scan ----
    for (int cidx = 0; cidx < NC; ++cidx) {
        const int t0 = cidx * Tc;
        gemm_gate4<<<dim3(32, B_ * (Tc / 128)), 256, 0, stream>>>(
            xnb, WT4, bias4, gx, t0, Tc);
        scan_kernel<<<64, 512, 0, stream>>>(
            gx, RQ, rb4, state, hbn, t0, Tc, cidx == 0 ? 1 : 0);
    }

    // ---- multihead LN (in place) ----
    mln_kernel<<<M_, 512, 0, stream>>>(hbn, hln_w, hln_b, hbn);

    // ---- FFN ----
    gemm_up_geglu<<<dim3(PPAD_ / 128, 128), 256, 0, stream>>>(hbn, W1T, W2T, up_b, gbuf);
    gemm_down_out<<<dim3(8, 128), 256, 0, stream>>>(gbuf, dnT, down_b, x, out, PPAD_, D_);

    (void)in_sizes; (void)n_in; (void)out_size;
}

// Round 3
// 1600.533 us; speedup vs baseline: 2.0319x; 1.2826x over previous
//
#include <hip/hip_runtime.h>

typedef unsigned short u16;
typedef __attribute__((ext_vector_type(4))) float v4f;
typedef __attribute__((ext_vector_type(8))) short bf16x8;

#define B_ 8
#define T_ 2048
#define D_ 1024
#define NH_ 8
#define DH_ 128
#define H_ 1024
#define P_ 1365
#define PPAD_ 1408   // P padded to multiple of 128 (up-GEMM N, down-GEMM K)
#define M_ 16384     // B*T

// ---------- bf16 helpers (manual RNE) ---------------------------------------
__device__ __forceinline__ u16 f2b(float f) {
    union { float f; unsigned u; } v; v.f = f;
    unsigned r = (v.u + 0x7fffu + ((v.u >> 16) & 1u)) >> 16;
    return (u16)r;
}
__device__ __forceinline__ float b2f(u16 u) {
    union { unsigned u; float f; } v; v.u = ((unsigned)u) << 16;
    return v.f;
}

// quad broadcast: every lane gets quad-lane S's value (full-rate DPP mov)
template<int S>
__device__ __forceinline__ float qb(float x) {
    return __int_as_float(__builtin_amdgcn_update_dpp(
        0, __float_as_int(x), S * 0x55, 0xF, 0xF, true));
}

// async global->LDS, 16B per lane; lds ptr must be wave-uniform
#define GLD16(gp, lp) __builtin_amdgcn_global_load_lds( \
    (const __attribute__((address_space(1))) void*)(gp), \
    (__attribute__((address_space(3))) void*)(lp), 16, 0, 0)

// ---------------- transpose + cast fp32 -> bf16 ------------------------------
// output row index = n*rowmul + rowoff (lets the 4 gate weights interleave
// their columns: WT4i[nh*4+g][k], so gate-GEMM output is [t][nh][g] packed)
__global__ __launch_bounds__(256) void transpose_cast(
    const float* __restrict__ in, u16* __restrict__ out,
    int K, int N, int Kpad, int Npad, int ldin, int rowmul, int rowoff)
{
    __shared__ float tile[32][33];
    const int tx = threadIdx.x, ty = threadIdx.y;
    const int nblk = blockIdx.x * 32, kblk = blockIdx.y * 32;
#pragma unroll
    for (int i = 0; i < 4; ++i) {
        int k = kblk + ty + i * 8, n = nblk + tx;
        float v = (k < K && n < N) ? in[(size_t)k * ldin + n] : 0.f;
        tile[ty + i * 8][tx] = v;
    }
    __syncthreads();
#pragma unroll
    for (int i = 0; i < 4; ++i) {
        int n = nblk + ty + i * 8, k = kblk + tx;
        if (n < Npad && k < Kpad)
            out[((size_t)n * rowmul + rowoff) * Kpad + k] = f2b(tile[tx][ty + i * 8]);
    }
}

// ---------------- concat 4 per-gate vectors [1024] -> interleaved [1024][4] -
__global__ __launch_bounds__(256) void bias4_concat(
    const float* __restrict__ bz, const float* __restrict__ bi,
    const float* __restrict__ bo, const float* __restrict__ bf,
    float* __restrict__ b4)
{
    int j = blockIdx.x * 256 + threadIdx.x;  // 0..4095
    const float* p = (j < 1024) ? bz : (j < 2048) ? bi : (j < 3072) ? bo : bf;
    b4[((j & 1023) << 2) | (j >> 10)] = p[j & 1023];
}

// ---------------- pack R into MFMA layout: RQ[hd][m=e*4+g][d] bf16 ----------
__global__ __launch_bounds__(128) void rq_prep(
    const float* __restrict__ Rz, const float* __restrict__ Ri,
    const float* __restrict__ Ro, const float* __restrict__ Rf,
    u16* __restrict__ RQ)
{
    const int m = blockIdx.x;      // 0..511
    const int hd = blockIdx.y;     // 0..7
    const int d = threadIdx.x;     // 0..127
    const int g = m & 3, e = m >> 2;
    const float* Rg = (g == 0) ? Rz : (g == 1) ? Ri : (g == 2) ? Ro : Rf;
    RQ[((size_t)hd * 512 + m) * 128 + d] =
        f2b(Rg[((size_t)hd * 128 + d) * 128 + e]);
}

// ---------------- LayerNorm over D=1024 + cast to bf16 ----------------------
__global__ __launch_bounds__(256) void ln_cast_kernel(
    const float* __restrict__ x, const float* __restrict__ w,
    const float* __restrict__ b, u16* __restrict__ xnb)
{
    const int token = blockIdx.x, tid = threadIdx.x;
    const float4* xr = (const float4*)(x + (size_t)token * D_);
    float4 v = xr[tid];
    float s  = v.x + v.y + v.z + v.w;
    float ss = v.x * v.x + v.y * v.y + v.z * v.z + v.w * v.w;
    for (int off = 32; off; off >>= 1) { s += __shfl_down(s, off); ss += __shfl_down(ss, off); }
    __shared__ float wsum[4], wsq[4], stats[2];
    const int wave = tid >> 6, lane = tid & 63;
    if (lane == 0) { wsum[wave] = s; wsq[wave] = ss; }
    __syncthreads();
    if (tid == 0) {
        float S = 0.f, SS = 0.f;
        for (int i = 0; i < 4; ++i) { S += wsum[i]; SS += wsq[i]; }
        float mu = S * (1.f / 1024.f);
        float var = SS * (1.f / 1024.f) - mu * mu;
        stats[0] = mu; stats[1] = rsqrtf(var + 1e-6f);
    }
    __syncthreads();
    const float mu = stats[0], rs = stats[1];
    float4 wv = ((const float4*)w)[tid];
    float4 bv = ((const float4*)b)[tid];
    ushort4 o;
    o.x = f2b((v.x - mu) * rs * wv.x + bv.x);
    o.y = f2b((v.y - mu) * rs * wv.y + bv.y);
    o.z = f2b((v.z - mu) * rs * wv.z + bv.z);
    o.w = f2b((v.w - mu) * rs * wv.w + bv.w);
    ((ushort4*)(xnb + (size_t)token * D_))[tid] = o;
}

// ---------------- m97-style bf16 MFMA GEMM core (128x128 tile, BK=32) -------
__device__ __forceinline__ void gemm128_core(
    const u16* __restrict__ A, const u16* __restrict__ BT,
    int K, int m0, int n0, v4f acc[4][4])
{
    __shared__ __align__(16) u16 As[4096];  // [128][32]
    __shared__ __align__(16) u16 Bs[4096];  // [128][32]
    const int tid = threadIdx.x;
    const int wave = tid >> 6, lane = tid & 63;
    const int wm = wave & 1, wn = wave >> 1;
    const int srow = tid >> 2, sseg = tid & 3;
    const int lm = lane & 15, lq = lane >> 4;

    const u16* gA0 = A  + (size_t)(m0 + srow) * K + sseg * 8;
    const u16* gA1 = gA0 + (size_t)64 * K;
    const u16* gB0 = BT + (size_t)(n0 + srow) * K + sseg * 8;
    const u16* gB1 = gB0 + (size_t)64 * K;
    u16* lA0 = As + wave * 512;
    u16* lA1 = As + 2048 + wave * 512;
    u16* lB0 = Bs + wave * 512;
    u16* lB1 = Bs + 2048 + wave * 512;

    for (int kk = 0; kk < K; kk += 32) {
        GLD16(gA0 + kk, lA0);
        GLD16(gA1 + kk, lA1);
        GLD16(gB0 + kk, lB0);
        GLD16(gB1 + kk, lB1);
        __syncthreads();
        bf16x8 a[4], b[4];
#pragma unroll
        for (int i = 0; i < 4; ++i) {
            a[i] = *(const bf16x8*)(As + (wm * 64 + i * 16 + lm) * 32 + lq * 8);
            b[i] = *(const bf16x8*)(Bs + (wn * 64 + i * 16 + lm) * 32 + lq * 8);
        }
#pragma unroll
        for (int i = 0; i < 4; ++i)
#pragma unroll
            for (int j = 0; j < 4; ++j)
                acc[i][j] = __builtin_amdgcn_mfma_f32_16x16x32_bf16(a[i], b[j], acc[i][j], 0, 0, 0);
        __syncthreads();
    }
}

// ---------------- fused 4-gate GEMM (N=4096, cols = nh*4+g interleaved) -----
__global__ __launch_bounds__(256) void gemm_gate4(
    const u16* __restrict__ A, const u16* __restrict__ WT4,
    const float* __restrict__ bias4, u16* __restrict__ gx4,
    int t0, int Tc)
{
    v4f acc[4][4];
#pragma unroll
    for (int i = 0; i < 4; ++i)
#pragma unroll
        for (int j = 0; j < 4; ++j)
#pragma unroll
            for (int r = 0; r < 4; ++r) acc[i][j][r] = 0.f;
    const int mtPerB = Tc >> 7;
    const int b_ = blockIdx.y / mtPerB, tt = blockIdx.y % mtPerB;
    const int m0 = b_ * T_ + t0 + tt * 128;
    const int n0 = blockIdx.x * 128;
    gemm128_core(A, WT4, D_, m0, n0, acc);
    const int r0 = b_ * Tc + tt * 128;   // row in chunk space
    const int tid = threadIdx.x, wave = tid >> 6, lane = tid & 63;
    const int wm = wave & 1, wn = wave >> 1;
    const int col = lane & 15, rb0 = (lane >> 4) * 4;
#pragma unroll
    for (int j = 0; j < 4; ++j) {
        const int n = n0 + wn * 64 + j * 16 + col;
        const float bv = bias4[n];
#pragma unroll
        for (int i = 0; i < 4; ++i)
#pragma unroll
            for (int r = 0; r < 4; ++r) {
                const int rr = r0 + wm * 64 + i * 16 + rb0 + r;
                gx4[(size_t)rr * 4096 + n] = f2b(acc[i][j][r] + bv);
            }
    }
}

// ---------------- MFMA sequential scan, operand-swapped matvec --------------
// One WG per (batch, head). 512 thr = 8 waves. Per step:
//   all lanes ds_read_b128 h chunk (broadcast, same addr per 16-lane group)
//   -> A-operand rows all equal h -> D[r][c] = matvec[64w+c] for every r
//   -> after 3-cndmask tile select, lane l holds matvec[64w+l]: gate g=l&3
//   of element e=16w+(l>>2) -- NO redistribution. Uniform 1-exp transform,
//   DPP quad-bcast, state update in regs of lanes l%4==0, write h (bf16)
//   to 256B double-buffered LDS -> ONE lgkm-only barrier (vmcnt never
//   drained; gx prefetch depth 4 rides across steps).
__global__ __launch_bounds__(512, 1) void scan_kernel(
    const u16* __restrict__ gx4,   // [B][Tc][4096] bf16, idx hd*512+e*4+g
    const u16* __restrict__ RQ,    // [8][512][128] bf16, rows m=e*4+g
    const float* __restrict__ rb4, // [1024][4] recurrent biases interleaved
    float* __restrict__ state,     // [64][128] float4 c,n,m,h
    u16* __restrict__ hraw,        // [M][H] bf16 raw h
    int t0, int Tc, int init)
{
    const int blk = blockIdx.x;           // 0..63
    const int b = blk >> 3, hd = blk & 7;
    const int tid = threadIdx.x;
    const int w = tid >> 6, lane = tid & 63;
    const int lm = lane & 15, lq = lane >> 4;
    const int g = lane & 3;               // gate handled by this lane (m=64w+lane)
    const int e = (w << 4) + (lane >> 2); // element of state lanes
    const bool st_lane = (g == 0);        // 16 lanes/wave own state

    // h double buffer: 128 bf16 each (written fully every step by all waves)
    __shared__ __align__(16) u16 hL[2][128];

    // B-operand fragments (R rows as cols): wave w covers m = 64w..64w+63
    bf16x8 rq[4][4];
    const u16* RQh = RQ + (size_t)hd * (512 * 128);
#pragma unroll
    for (int i = 0; i < 4; ++i)
#pragma unroll
        for (int kc = 0; kc < 4; ++kc)
            rq[i][kc] = *(const bf16x8*)(RQh +
                (size_t)(w * 64 + i * 16 + lm) * 128 + kc * 32 + lq * 8);

    // per-lane gate constants: tanh / 15*tanh(./15) / sigmoid, all as
    //   K0 - K1 * rcp(exp(K2*x) + 1)
    const float K0 = (g == 1 || g == 3) ? 15.f : 1.f;
    const float K1 = (g == 0) ? 2.f : (g == 2) ? 1.f : 30.f;
    const float K2 = (g == 0) ? 2.f : (g == 2) ? 1.f : (2.f / 15.f);
    const float rb_l = rb4[(hd << 9) + (w << 6) + lane];

    float cS = 0.f, nS = 1.f, mS = 0.f, hS = 0.f;
    if (st_lane && !init) {
        float4 s = ((const float4*)state)[(blk << 7) + e];
        cS = s.x; nS = s.y; mS = s.z; hS = s.w;
    }

    if (st_lane) hL[0][e] = f2b(hS);
    __syncthreads();

    const u16* gxb = gx4 + (size_t)b * Tc * 4096 + (hd << 9) + (w << 6) + lane;
    u16* houtp = hraw + (size_t)(b * T_ + t0) * H_ + (hd << 7) + e;

    // prefetch gate preacts depth 4 (1 u16 per lane per step, coalesced)
    u16 pgA = gxb[0], pgB = gxb[4096], pgC = gxb[2 * 4096], pgD = gxb[3 * 4096];

#define SCAN_STEP(TL, RB, WB, PG)                                              \
    {                                                                          \
        /* h as A-operand: same chunk for all 16 lanes of a quad-col group */  \
        const bf16x8 hv0 = *(const bf16x8*)(&hL[RB][0 * 32 + lq * 8]);         \
        const bf16x8 hv1 = *(const bf16x8*)(&hL[RB][1 * 32 + lq * 8]);         \
        const bf16x8 hv2 = *(const bf16x8*)(&hL[RB][2 * 32 + lq * 8]);         \
        const bf16x8 hv3 = *(const bf16x8*)(&hL[RB][3 * 32 + lq * 8]);         \
        v4f p0[4], p1[4];                                                      \
        _Pragma("unroll") for (int i = 0; i < 4; ++i)                          \
            _Pragma("unroll") for (int r = 0; r < 4; ++r) {                    \
                p0[i][r] = 0.f; p1[i][r] = 0.f; }                              \
        _Pragma("unroll") for (int i = 0; i < 4; ++i) {                        \
            p0[i] = __builtin_amdgcn_mfma_f32_16x16x32_bf16(hv0, rq[i][0], p0[i], 0, 0, 0); \
            p1[i] = __builtin_amdgcn_mfma_f32_16x16x32_bf16(hv1, rq[i][1], p1[i], 0, 0, 0); \
            p0[i] = __builtin_amdgcn_mfma_f32_16x16x32_bf16(hv2, rq[i][2], p0[i], 0, 0, 0); \
            p1[i] = __builtin_amdgcn_mfma_f32_16x16x32_bf16(hv3, rq[i][3], p1[i], 0, 0, 0); \
        }                                                                      \
        const float s0 = p0[0][0] + p1[0][0];                                  \
        const float s1 = p0[1][0] + p1[1][0];                                  \
        const float s2 = p0[2][0] + p1[2][0];                                  \
        const float s3 = p0[3][0] + p1[3][0];                                  \
        const float sel = (lq & 2) ? ((lq & 1) ? s3 : s2)                      \
                                   : ((lq & 1) ? s1 : s0);                     \
        const int tn = ((TL) + 4 < Tc) ? (TL) + 4 : Tc - 1;                    \
        const u16 pgn = gxb[(size_t)tn * 4096];                                \
        const float pre = sel + b2f(PG) + rb_l;                                \
        PG = pgn;                                                              \
        const float tt = K0 - K1 * __builtin_amdgcn_rcpf(__expf(pre * K2) + 1.f); \
        const float ipv = qb<1>(tt);                                           \
        const float ovv = qb<2>(tt);                                           \
        const float fpv = qb<3>(tt);                                           \
        if (st_lane) {                                                         \
            const float bm = fpv + mS;                                         \
            const float d  = ipv - bm;                                         \
            const float mt = fmaxf(bm, ipv);                                   \
            const float e1 = __expf(-fabsf(d));                                \
            const float ig = (d >= 0.f) ? 1.f : e1;                            \
            const float fg = (d >= 0.f) ? e1 : 1.f;                            \
            cS = fg * cS + ig * tt;                                            \
            nS = fg * nS + ig;                                                 \
            mS = mt;                                                           \
            const float hv = ovv * cS * __builtin_amdgcn_rcpf(fmaxf(nS, 1.f)); \
            hS = hv;                                                           \
            const u16 hb = f2b(hv);                                            \
            hL[WB][e] = hb;                                                    \
            houtp[(size_t)(TL) * H_] = hb;                                     \
        }                                                                      \
        asm volatile("s_waitcnt lgkmcnt(0)" ::: "memory");                     \
        __builtin_amdgcn_s_barrier();                                          \
        __builtin_amdgcn_sched_barrier(0);                                     \
    }

    for (int tl = 0; tl < Tc; tl += 4) {
        SCAN_STEP(tl,     0, 1, pgA)
        SCAN_STEP(tl + 1, 1, 0, pgB)
        SCAN_STEP(tl + 2, 0, 1, pgC)
        SCAN_STEP(tl + 3, 1, 0, pgD)
    }
#undef SCAN_STEP

    if (st_lane) {
        ((float4*)state)[(blk << 7) + e] = make_float4(cS, nS, mS, hS);
    }
}

// ---------------- multihead layernorm (in-place capable) --------------------
__global__ __launch_bounds__(512) void mln_kernel(
    const u16* __restrict__ h_all, const float* __restrict__ w,
    const float* __restrict__ b, u16* __restrict__ hb)
{
    const int token = blockIdx.x, tid = threadIdx.x;
    const int wave = tid >> 6, lane = tid & 63;
    const u16* hr = h_all + (size_t)token * H_ + wave * DH_;
    float a0 = b2f(hr[lane]), a1 = b2f(hr[64 + lane]);
    float s = a0 + a1, ss = a0 * a0 + a1 * a1;
    for (int off = 32; off; off >>= 1) { s += __shfl_xor(s, off); ss += __shfl_xor(ss, off); }
    const float mu = s * (1.f / 128.f);
    const float var = ss * (1.f / 128.f) - mu * mu;
    const float rs = rsqrtf(var + 1e-6f);
    const int c0 = wave * DH_ + lane;
    u16* hw = hb + (size_t)token * H_ + wave * DH_;
    hw[lane]      = f2b((a0 - mu) * rs * w[c0] + b[c0]);
    hw[64 + lane] = f2b((a1 - mu) * rs * w[c0 + 64] + b[c0 + 64]);
}

// ---------------- up-GEMM with fused GEGLU ----------------------------------
__global__ __launch_bounds__(256) void gemm_up_geglu(
    const u16* __restrict__ A, const u16* __restrict__ B1T,
    const u16* __restrict__ B2T, const float* __restrict__ upb,
    u16* __restrict__ G)
{
    __shared__ __align__(16) u16 As[4096], B1s[4096], B2s[4096];
    v4f acc1[4][4], acc2[4][4];
#pragma unroll
    for (int i = 0; i < 4; ++i)
#pragma unroll
        for (int j = 0; j < 4; ++j)
#pragma unroll
            for (int r = 0; r < 4; ++r) { acc1[i][j][r] = 0.f; acc2[i][j][r] = 0.f; }
    const int m0 = blockIdx.y * 128, n0 = blockIdx.x * 128;
    const int tid = threadIdx.x;
    const int wave = tid >> 6, lane = tid & 63;
    const int wm = wave & 1, wn = wave >> 1;
    const int srow = tid >> 2, sseg = tid & 3;
    const int lm = lane & 15, lq = lane >> 4;

    const u16* gA0 = A   + (size_t)(m0 + srow) * H_ + sseg * 8;
    const u16* gA1 = gA0 + (size_t)64 * H_;
    const u16* g10 = B1T + (size_t)(n0 + srow) * H_ + sseg * 8;
    const u16* g11 = g10 + (size_t)64 * H_;
    const u16* g20 = B2T + (size_t)(n0 + srow) * H_ + sseg * 8;
    const u16* g21 = g20 + (size_t)64 * H_;
    u16* lA0 = As  + wave * 512;        u16* lA1 = As  + 2048 + wave * 512;
    u16* l10 = B1s + wave * 512;        u16* l11 = B1s + 2048 + wave * 512;
    u16* l20 = B2s + wave * 512;        u16* l21 = B2s + 2048 + wave * 512;

    for (int kk = 0; kk < H_; kk += 32) {
        GLD16(gA0 + kk, lA0); GLD16(gA1 + kk, lA1);
        GLD16(g10 + kk, l10); GLD16(g11 + kk, l11);
        GLD16(g20 + kk, l20); GLD16(g21 + kk, l21);
        __syncthreads();
        bf16x8 a[4], b1[4], b2[4];
#pragma unroll
        for (int i = 0; i < 4; ++i) {
            a[i]  = *(const bf16x8*)(As  + (wm * 64 + i * 16 + lm) * 32 + lq * 8);
            b1[i] = *(const bf16x8*)(B1s + (wn * 64 + i * 16 + lm) * 32 + lq * 8);
            b2[i] = *(const bf16x8*)(B2s + (wn * 64 + i * 16 + lm) * 32 + lq * 8);
        }
#pragma unroll
        for (int i = 0; i < 4; ++i)
#pragma unroll
            for (int j = 0; j < 4; ++j) {
                acc1[i][j] = __builtin_amdgcn_mfma_f32_16x16x32_bf16(a[i], b1[j], acc1[i][j], 0, 0, 0);
                acc2[i][j] = __builtin_amdgcn_mfma_f32_16x16x32_bf16(a[i], b2[j], acc2[i][j], 0, 0, 0);
            }
        __syncthreads();
    }
    const int col = lane & 15, rb0 = (lane >> 4) * 4;
#pragma unroll
    for (int j = 0; j < 4; ++j) {
        const int n = n0 + wn * 64 + j * 16 + col;
        const bool ok = (n < P_);
        const float bb1 = ok ? upb[n] : 0.f;
        const float bb2 = ok ? upb[P_ + n] : 0.f;
#pragma unroll
        for (int i = 0; i < 4; ++i)
#pragma unroll
            for (int r = 0; r < 4; ++r) {
                const int mm = m0 + wm * 64 + i * 16 + rb0 + r;
                float gval = 0.f;
                if (ok) {
                    const float u1 = acc1[i][j][r] + bb1;
                    const float u2 = acc2[i][j][r] + bb2;
                    const float ge = 0.5f * u2 * (1.f + erff(u2 * 0.70710678118654752f));
                    gval = u1 * ge;
                }
                G[(size_t)mm * PPAD_ + n] = f2b(gval);
            }
    }
}

// ---------------- down GEMM -> fp32 out with bias + residual ----------------
__global__ __launch_bounds__(256) void gemm_down_out(
    const u16* __restrict__ A, const u16* __restrict__ BT,
    const float* __restrict__ bias, const float* __restrict__ resid,
    float* __restrict__ C, int K, int ldc)
{
    v4f acc[4][4];
#pragma unroll
    for (int i = 0; i < 4; ++i)
#pragma unroll
        for (int j = 0; j < 4; ++j)
#pragma unroll
            for (int r = 0; r < 4; ++r) acc[i][j][r] = 0.f;
    const int m0 = blockIdx.y * 128, n0 = blockIdx.x * 128;
    gemm128_core(A, BT, K, m0, n0, acc);
    const int tid = threadIdx.x, wave = tid >> 6, lane = tid & 63;
    const int wm = wave & 1, wn = wave >> 1;
    const int col = lane & 15, rb0 = (lane >> 4) * 4;
#pragma unroll
    for (int j = 0; j < 4; ++j) {
        const int n = n0 + wn * 64 + j * 16 + col;
        const float bv = bias[n];
#pragma unroll
        for (int i = 0; i < 4; ++i)
#pragma unroll
            for (int r = 0; r < 4; ++r) {
                const int mm = m0 + wm * 64 + i * 16 + rb0 + r;
                C[(size_t)mm * ldc + n] = acc[i][j][r] + bv + resid[(size_t)mm * ldc + n];
            }
    }
}

// ============================ launcher ======================================
extern "C" void kernel_launch(void* const* d_in, const int* in_sizes, int n_in,
                              void* d_out, int out_size, void* d_ws, size_t ws_size,
                              hipStream_t stream)
{
    const float* x     = (const float*)d_in[0];
    const float* ln_w  = (const float*)d_in[1];
    const float* ln_b  = (const float*)d_in[2];
    const float* hln_w = (const float*)d_in[3];
    const float* hln_b = (const float*)d_in[4];
    const float* Wz = (const float*)d_in[5];  const float* bz  = (const float*)d_in[6];
    const float* Wi = (const float*)d_in[7];  const float* bi  = (const float*)d_in[8];
    const float* Wo = (const float*)d_in[9];  const float* bo  = (const float*)d_in[10];
    const float* Wf = (const float*)d_in[11]; const float* bfv = (const float*)d_in[12];
    const float* Rz = (const float*)d_in[13]; const float* rbz = (const float*)d_in[14];
    const float* Ri = (const float*)d_in[15]; const float* rbi = (const float*)d_in[16];
    const float* Ro = (const float*)d_in[17]; const float* rbo = (const float*)d_in[18];
    const float* Rf = (const float*)d_in[19]; const float* rbf = (const float*)d_in[20];
    const float* up_w   = (const float*)d_in[21]; const float* up_b   = (const float*)d_in[22];
    const float* down_w = (const float*)d_in[23]; const float* down_b = (const float*)d_in[24];
    float* out = (float*)d_out;

    // ---- workspace layout (adaptive to ws_size) ----
    size_t off = 0;
    char* base = (char*)d_ws;
    auto alloc = [&](size_t bytes) -> char* {
        char* r = base + off; off += (bytes + 255) & ~(size_t)255; return r;
    };
    u16*   WT4   = (u16*)  alloc((size_t)4 * H_ * D_ * 2);      // 8 MiB (interleaved cols)
    u16*   W1T   = (u16*)  alloc((size_t)PPAD_ * H_ * 2);       // 2.75 MiB
    u16*   W2T   = (u16*)  alloc((size_t)PPAD_ * H_ * 2);       // 2.75 MiB
    u16*   dnT   = (u16*)  alloc((size_t)D_ * PPAD_ * 2);       // 2.75 MiB
    u16*   RQ    = (u16*)  alloc((size_t)8 * 512 * 128 * 2);    // 1 MiB
    float* bias4 = (float*)alloc(4096 * 4);
    float* rb4   = (float*)alloc(4096 * 4);
    float* state = (float*)alloc((size_t)64 * 4 * 128 * 4);     // 128 KiB
    u16*   hbn   = (u16*)  alloc((size_t)M_ * H_ * 2);          // 32 MiB
    char*  dyn   = base + off;
    u16*   xnb   = (u16*)dyn;                                   // 32 MiB
    const size_t xnb_bytes = (size_t)M_ * H_ * 2;
    u16*   gbuf  = (u16*)dyn;  // overlays xnb+gx (both dead by up-GEMM time)

    // pick largest Tc whose gx chunk fits
    const size_t fixed = off + xnb_bytes;
    int Tc = 256;
    if      (ws_size >= fixed + (size_t)4 * B_ * 2048 * H_ * 2) Tc = 2048;
    else if (ws_size >= fixed + (size_t)4 * B_ * 1024 * H_ * 2) Tc = 1024;
    else if (ws_size >= fixed + (size_t)4 * B_ * 512  * H_ * 2) Tc = 512;
    u16* gx = (u16*)(dyn + xnb_bytes);
    const int NC = T_ / Tc;

    // ---- weight prep ----
    dim3 tb(32, 8);
    const float* Ws[4] = {Wz, Wi, Wo, Wf};
    for (int g = 0; g < 4; ++g)
        transpose_cast<<<dim3(32, 32), tb, 0, stream>>>(
            Ws[g], WT4, D_, H_, D_, H_, H_, 4, g);   // col-interleaved rows nh*4+g
    transpose_cast<<<dim3(44, 32), tb, 0, stream>>>(up_w,      W1T, H_, P_, H_, PPAD_, 2 * P_, 1, 0);
    transpose_cast<<<dim3(44, 32), tb, 0, stream>>>(up_w + P_, W2T, H_, P_, H_, PPAD_, 2 * P_, 1, 0);
    transpose_cast<<<dim3(32, 44), tb, 0, stream>>>(down_w, dnT, P_, D_, PPAD_, D_, D_, 1, 0);
    bias4_concat<<<16, 256, 0, stream>>>(bz, bi, bo, bfv, bias4);
    bias4_concat<<<16, 256, 0, stream>>>(rbz, rbi, rbo, rbf, rb4);
    rq_prep<<<dim3(512, 8), 128, 0, stream>>>(Rz, Ri, Ro, Rf, RQ);

    // ---- input LN ----
    ln_cast_kernel<<<M_, 256, 0, stream>>>(x, ln_w, ln_b, xnb);

    // ---- chunked gate GEMM + scan ----
    for (int cidx = 0; cidx < NC; ++cidx) {
        const int t0 = cidx * Tc;
        gemm_gate4<<<dim3(32, B_ * (Tc / 128)), 256, 0, stream>>>(
            xnb, WT4, bias4, gx, t0, Tc);
        scan_kernel<<<64, 512, 0, stream>>>(
            gx, RQ, rb4, state, hbn, t0, Tc, cidx == 0 ? 1 : 0);
    }

    // ---- multihead LN (in place) ----
    mln_kernel<<<M_, 512, 0, stream>>>(hbn, hln_w, hln_b, hbn);

    // ---- FFN ----
    gemm_up_geglu<<<dim3(PPAD_ / 128, 128), 256, 0, stream>>>(hbn, W1T, W2T, up_b, gbuf);
    gemm_down_out<<<dim3(8, 128), 256, 0, stream>>>(gbuf, dnT, down_b, x, out, PPAD_, D_);

    (void)in_sizes; (void)n_in; (void)out_size;
}